// Round 4
// baseline (921.328 us; speedup 1.0000x reference)
//
#include <hip/hip_runtime.h>

// Problem constants
#define BB   64
#define NN   4096
#define EE   8192
#define DD   256
#define HH   256
#define MM   64
#define K1   512          // 2*D
#define NC   384          // H + 128 fused GEMM1 cols
#define TE   64           // edges per block
#define BLOCK 512         // 8 waves
#define KC   64           // k-elems per chunk (2 MFMA k-steps)
#define NCHUNK 8          // K1/KC (old path)
#define ASTR 88           // shorts per A row (64 + 24 pad)
#define GSTR 136          // shorts per Gs row (128 + 8 pad)
#define ABUF (64 * ASTR)  // 5632 shorts per A buffer
#define SMEM_SHORTS (2 * ABUF)
#define BE_TOT (BB * EE)  // 524288
#define WCTF_ELEMS (NC * K1)   // 196608 (old fused layout; same count as new 768x256)
#define A2F_ELEMS  (128 * MM)  // 8192
#define WS_FRAG ((size_t)(WCTF_ELEMS + A2F_ELEMS) * sizeof(short))  // 409600
// New path: pre[B*N] rows of 2048B = 512 bf16 (Hsrc|Htgt) + 256 f32 (Gsrc|Gtgt)
#define PRE_ROW 2048
#define WS_PRE ((size_t)BB * NN * PRE_ROW)          // 536870912
#define WS_BIG (WS_FRAG + WS_PRE)

typedef float f32x4 __attribute__((ext_vector_type(4)));
typedef short bf16x8 __attribute__((ext_vector_type(8)));

__device__ __forceinline__ short f2bf(float f) {
    unsigned u = __float_as_uint(f);
    unsigned r = (u + 0x7fffu + ((u >> 16) & 1u)) >> 16;
    return (short)r;
}
__device__ __forceinline__ float bf2f(short s) {
    return __uint_as_float(((unsigned)(unsigned short)s) << 16);
}
__device__ __forceinline__ int cvt_pk_bf16(float lo, float hi) {
    int r;
    asm("v_cvt_pk_bf16_f32 %0, %1, %2" : "=v"(r) : "v"(lo), "v"(hi));
    return r;
}
// Barrier that only drains LDS ops — global loads stay in flight.
__device__ __forceinline__ void barrier_lgkm() {
    asm volatile("s_waitcnt lgkmcnt(0)\n\ts_barrier" ::: "memory");
}

// ================= OLD PATH (R3, proven) =================

__global__ void AttackHead_prep(const float* __restrict__ W1,
                                const float* __restrict__ A1,
                                const float* __restrict__ A2,
                                short* __restrict__ wctf,
                                short* __restrict__ a2f) {
    int t = blockIdx.x * 256 + threadIdx.x;
    if (t < 131072) {
        int k = t >> 8, n = t & 255;
        int c = k >> 5, kr = k & 31, quad = kr >> 3, j = kr & 7;
        int nt = n >> 4, l15 = n & 15;
        wctf[((c * 24 + nt) * 64 + quad * 16 + l15) * 8 + j] = f2bf(W1[t]);
    } else if (t < 131072 + 65536) {
        int t2 = t - 131072;
        int k = t2 >> 7, n = 256 + (t2 & 127);
        int c = k >> 5, kr = k & 31, quad = kr >> 3, j = kr & 7;
        int nt = n >> 4, l15 = n & 15;
        wctf[((c * 24 + nt) * 64 + quad * 16 + l15) * 8 + j] = f2bf(A1[t2]);
    } else if (t < 131072 + 65536 + 8192) {
        int t3 = t - 131072 - 65536;
        int k = t3 >> 6, n = t3 & 63;
        int ks = k >> 5, kr = k & 31, quad = kr >> 3, j = kr & 7;
        int nt2 = n >> 4, l15 = n & 15;
        a2f[((ks * 4 + nt2) * 64 + quad * 16 + l15) * 8 + j] = f2bf(A2[t3]);
    }
}

template <bool USE_WS>
__device__ __forceinline__ bf16x8 load_bfrag(const short* __restrict__ wf,
                                             const float* __restrict__ W1,
                                             const float* __restrict__ A1,
                                             int c, int nt, int lane) {
    if (USE_WS) {
        return *(const bf16x8*)(wf + ((c * 24 + nt) * 64 + lane) * 8);
    } else {
        int l15 = lane & 15, quad = lane >> 4;
        int n = nt * 16 + l15;
        bf16x8 r;
        #pragma unroll
        for (int j = 0; j < 8; ++j) {
            int k = c * 32 + quad * 8 + j;
            float v = (n < HH) ? W1[k * HH + n] : A1[k * 128 + (n - HH)];
            r[j] = f2bf(v);
        }
        return r;
    }
}

template <bool USE_WS>
__device__ __forceinline__ bf16x8 load_a2frag(const short* __restrict__ a2f,
                                              const float* __restrict__ A2,
                                              int ks, int nt2, int lane) {
    if (USE_WS) {
        return *(const bf16x8*)(a2f + ((ks * 4 + nt2) * 64 + lane) * 8);
    } else {
        int l15 = lane & 15, quad = lane >> 4;
        int n = nt2 * 16 + l15;
        bf16x8 r;
        #pragma unroll
        for (int j = 0; j < 8; ++j) {
            int k = ks * 32 + quad * 8 + j;
            r[j] = f2bf(A2[k * MM + n]);
        }
        return r;
    }
}

template <bool USE_WS>
__global__ __launch_bounds__(BLOCK, 4)
void AttackHead_main(const float* __restrict__ nodes,
                     const float* __restrict__ army,
                     const int* __restrict__ edges,
                     const float* __restrict__ W1,
                     const float* __restrict__ b1,
                     const float* __restrict__ W2,
                     const float* __restrict__ b2,
                     const float* __restrict__ A1,
                     const float* __restrict__ a1,
                     const float* __restrict__ A2,
                     const float* __restrict__ a2,
                     const short* __restrict__ wctf,
                     const short* __restrict__ a2f,
                     float* __restrict__ out) {
    __shared__ __align__(16) short smem[SMEM_SHORTS];
    __shared__ int   srcn[TE], tgtn[TE];
    __shared__ float elog[TE], maxs[TE];

    const int tid = threadIdx.x;
    const int bb  = ((blockIdx.x & 7) << 10) | (blockIdx.x >> 3);
    const int bglob = bb >> 7;
    const long be0 = (long)bb * TE;

    if (tid < TE) {
        long be = be0 + tid;
        int src = edges[2 * be], tgt = edges[2 * be + 1];
        int sc = min(max(src, 0), NN - 1);
        int tc = min(max(tgt, 0), NN - 1);
        srcn[tid] = sc; tgtn[tid] = tc;
        float sa = army[(size_t)bglob * NN + sc];
        float ta = army[(size_t)bglob * NN + tc];
        bool valid = (src >= 0) && (tgt >= 0);
        bool bad   = valid && (sa <= 2.0f || ta >= 3.0f * sa);
        bool selfe = valid && (src == tgt);
        elog[tid] = b2[0] - (bad ? 1.0f : 0.0f) - (selfe ? 100.0f : 0.0f);
        maxs[tid] = sa - 1.0f;
    }

    const int w    = tid >> 6;
    const int lane = tid & 63;
    const int quad = lane >> 4;
    const int l15  = lane & 15;

    bf16x8 bfc0 = load_bfrag<USE_WS>(wctf, W1, A1, 0, w * 3 + 0, lane);
    bf16x8 bfc1 = load_bfrag<USE_WS>(wctf, W1, A1, 0, w * 3 + 1, lane);
    bf16x8 bfc2 = load_bfrag<USE_WS>(wctf, W1, A1, 0, w * 3 + 2, lane);

    __syncthreads();

    const int srow = tid >> 3;
    const int sj   = tid & 7;
    const size_t nbase_g = (size_t)bglob * NN;
    const float* srcp = nodes + (nbase_g + (size_t)srcn[srow]) * DD + sj * 8;
    const float* tgtp = nodes + (nbase_g + (size_t)tgtn[srow]) * DD + sj * 8;

    f32x4 acc[4][3] = {};

    {
        float4 v0 = *(const float4*)(srcp);
        float4 v1 = *(const float4*)(srcp + 4);
        int4 s;
        s.x = cvt_pk_bf16(v0.x, v0.y); s.y = cvt_pk_bf16(v0.z, v0.w);
        s.z = cvt_pk_bf16(v1.x, v1.y); s.w = cvt_pk_bf16(v1.z, v1.w);
        *(int4*)(&smem[srow * ASTR + sj * 8]) = s;
    }
    float4 lda0 = *(const float4*)(srcp + 64);
    float4 lda1 = *(const float4*)(srcp + 68);

    #pragma unroll
    for (int c = 0; c < NCHUNK; ++c) {
        barrier_lgkm();

        float4 ldn0, ldn1;
        if (c + 2 < NCHUNK) {
            const float* p = ((c + 2) < 4 ? srcp : tgtp) + ((c + 2) & 3) * 64;
            ldn0 = *(const float4*)(p);
            ldn1 = *(const float4*)(p + 4);
        }

        bf16x8 bg0 = load_bfrag<USE_WS>(wctf, W1, A1, 2 * c + 1, w * 3 + 0, lane);
        bf16x8 bg1 = load_bfrag<USE_WS>(wctf, W1, A1, 2 * c + 1, w * 3 + 1, lane);
        bf16x8 bg2 = load_bfrag<USE_WS>(wctf, W1, A1, 2 * c + 1, w * 3 + 2, lane);

        const short* Ab = &smem[(c & 1) * ABUF];

        bf16x8 af[4];
        #pragma unroll
        for (int mt = 0; mt < 4; ++mt)
            af[mt] = *(const bf16x8*)(&Ab[(mt * 16 + l15) * ASTR + quad * 8]);
        #pragma unroll
        for (int mt = 0; mt < 4; ++mt) {
            acc[mt][0] = __builtin_amdgcn_mfma_f32_16x16x32_bf16(af[mt], bfc0, acc[mt][0], 0, 0, 0);
            acc[mt][1] = __builtin_amdgcn_mfma_f32_16x16x32_bf16(af[mt], bfc1, acc[mt][1], 0, 0, 0);
            acc[mt][2] = __builtin_amdgcn_mfma_f32_16x16x32_bf16(af[mt], bfc2, acc[mt][2], 0, 0, 0);
        }

        if (c + 1 < NCHUNK) {
            bfc0 = load_bfrag<USE_WS>(wctf, W1, A1, 2 * c + 2, w * 3 + 0, lane);
            bfc1 = load_bfrag<USE_WS>(wctf, W1, A1, 2 * c + 2, w * 3 + 1, lane);
            bfc2 = load_bfrag<USE_WS>(wctf, W1, A1, 2 * c + 2, w * 3 + 2, lane);
        }

        bf16x8 ag[4];
        #pragma unroll
        for (int mt = 0; mt < 4; ++mt)
            ag[mt] = *(const bf16x8*)(&Ab[(mt * 16 + l15) * ASTR + 32 + quad * 8]);
        #pragma unroll
        for (int mt = 0; mt < 4; ++mt) {
            acc[mt][0] = __builtin_amdgcn_mfma_f32_16x16x32_bf16(ag[mt], bg0, acc[mt][0], 0, 0, 0);
            acc[mt][1] = __builtin_amdgcn_mfma_f32_16x16x32_bf16(ag[mt], bg1, acc[mt][1], 0, 0, 0);
            acc[mt][2] = __builtin_amdgcn_mfma_f32_16x16x32_bf16(ag[mt], bg2, acc[mt][2], 0, 0, 0);
        }

        if (c + 1 < NCHUNK) {
            int4 s;
            s.x = cvt_pk_bf16(lda0.x, lda0.y); s.y = cvt_pk_bf16(lda0.z, lda0.w);
            s.z = cvt_pk_bf16(lda1.x, lda1.y); s.w = cvt_pk_bf16(lda1.z, lda1.w);
            *(int4*)(&smem[((c + 1) & 1) * ABUF + srow * ASTR + sj * 8]) = s;
        }
        if (c + 2 < NCHUNK) { lda0 = ldn0; lda1 = ldn1; }
    }

    __syncthreads();

    short* Gs = smem;
    float ep[4][4] = {};
    #pragma unroll
    for (int jn = 0; jn < 3; ++jn) {
        int ct = (w * 3 + jn) * 16 + l15;
        float bias = (ct < HH) ? b1[ct] : a1[ct - HH];
        if (ct < HH) {
            float w2v = W2[ct];
            #pragma unroll
            for (int mt = 0; mt < 4; ++mt)
                #pragma unroll
                for (int r = 0; r < 4; ++r) {
                    float h = fmaxf(acc[mt][jn][r] + bias, 0.0f);
                    ep[mt][r] += h * w2v;
                }
        } else {
            int gc = ct - HH;
            #pragma unroll
            for (int mt = 0; mt < 4; ++mt)
                #pragma unroll
                for (int r = 0; r < 4; ++r) {
                    float g = fmaxf(acc[mt][jn][r] + bias, 0.0f);
                    Gs[(mt * 16 + quad * 4 + r) * GSTR + gc] = f2bf(g);
                }
        }
    }
    if (w < 6) {
        #pragma unroll
        for (int msk = 1; msk <= 8; msk <<= 1)
            #pragma unroll
            for (int mt = 0; mt < 4; ++mt)
                #pragma unroll
                for (int r = 0; r < 4; ++r)
                    ep[mt][r] += __shfl_xor(ep[mt][r], msk, 64);
        if (l15 == 0) {
            #pragma unroll
            for (int mt = 0; mt < 4; ++mt)
                #pragma unroll
                for (int r = 0; r < 4; ++r)
                    atomicAdd(&elog[mt * 16 + quad * 4 + r], ep[mt][r]);
        }
    }
    __syncthreads();

    const int mt2 = w >> 1;
    const int nh  = w & 1;
    f32x4 acc2[2] = {};
    #pragma unroll
    for (int ks = 0; ks < 4; ++ks) {
        bf16x8 ga = *(const bf16x8*)(&Gs[(mt2 * 16 + l15) * GSTR + ks * 32 + quad * 8]);
        #pragma unroll
        for (int nb = 0; nb < 2; ++nb) {
            bf16x8 bv = load_a2frag<USE_WS>(a2f, A2, ks, nh * 2 + nb, lane);
            acc2[nb] = __builtin_amdgcn_mfma_f32_16x16x32_bf16(ga, bv, acc2[nb], 0, 0, 0);
        }
    }

    if (tid < TE) out[be0 + tid] = elog[tid];

    #pragma unroll
    for (int nb = 0; nb < 2; ++nb) {
        int col = (nh * 2 + nb) * 16 + l15;
        float a2v = a2[col];
        #pragma unroll
        for (int r = 0; r < 4; ++r) {
            int grow = mt2 * 16 + quad * 4 + r;
            float val = acc2[nb][r] + a2v;
            if ((float)col > maxs[grow]) val = -1e9f;
            out[(size_t)BE_TOT + (size_t)(be0 + grow) * MM + col] = val;
        }
    }
}

// ================= NEW PATH: per-node precompute =================
// pre[v] (2048B row): [0,512)=Hsrc bf16 cols 0..255; [512,1024)=Htgt bf16 cols 256..511
// (byte = 2*col for col<512); [1024,1536)=Gsrc f32 (cols 512..639);
// [1536,2048)=Gtgt f32 (cols 640..767); byte = 1024 + 4*(col-512).

// Prep2: wctf2 = B-fragments of Wcat [k=256][n=768]
__global__ void AttackHead_prep2(const float* __restrict__ W1,
                                 const float* __restrict__ A1,
                                 const float* __restrict__ A2,
                                 short* __restrict__ wctf2,
                                 short* __restrict__ a2f) {
    int t = blockIdx.x * 256 + threadIdx.x;
    if (t < 196608) {
        int k = t / 768, n = t - k * 768;
        float v;
        if (n < 256)       v = W1[k * 256 + n];                    // Hsrc
        else if (n < 512)  v = W1[(256 + k) * 256 + (n - 256)];    // Htgt
        else if (n < 640)  v = A1[k * 128 + (n - 512)];            // Gsrc
        else               v = A1[(256 + k) * 128 + (n - 640)];    // Gtgt
        int c = k >> 5, kr = k & 31, quad = kr >> 3, j = kr & 7;
        int nt = n >> 4, l15 = n & 15;
        wctf2[((c * 48 + nt) * 64 + quad * 16 + l15) * 8 + j] = f2bf(v);
    } else if (t < 196608 + 8192) {
        int t3 = t - 196608;
        int k = t3 >> 6, n = t3 & 63;
        int ks = k >> 5, kr = k & 31, quad = kr >> 3, j = kr & 7;
        int nt2 = n >> 4, l15 = n & 15;
        a2f[((ks * 4 + nt2) * 64 + quad * 16 + l15) * 8 + j] = f2bf(A2[t3]);
    }
}

// Dense GEMM: pre[262144, 768] = nodes(bf16) @ Wcat. Block: 64 rows x 384 cols.
__global__ __launch_bounds__(512, 4)
void AttackHead_pregemm(const float* __restrict__ nodes,
                        const short* __restrict__ wctf2,
                        char* __restrict__ pre) {
    __shared__ __align__(16) short smem[SMEM_SHORTS];
    const int tid = threadIdx.x;
    // XCD-contiguous: consecutive bb (both col-halves of a rowgrp) on same XCD.
    const int bb = ((blockIdx.x & 7) << 10) | (blockIdx.x >> 3);
    const int rowgrp = bb >> 1;
    const int nhalf  = bb & 1;

    const int w    = tid >> 6;
    const int lane = tid & 63;
    const int quad = lane >> 4;
    const int l15  = lane & 15;
    const int srow = tid >> 3;
    const int sj   = tid & 7;

    const float* Arowp = nodes + ((size_t)rowgrp * 64 + srow) * 256 + sj * 8;
    const int ntb = nhalf * 24 + w * 3;   // wave's first global n-tile (0..47)

    bf16x8 bfc0 = *(const bf16x8*)(wctf2 + ((0 * 48 + ntb + 0) * 64 + lane) * 8);
    bf16x8 bfc1 = *(const bf16x8*)(wctf2 + ((0 * 48 + ntb + 1) * 64 + lane) * 8);
    bf16x8 bfc2 = *(const bf16x8*)(wctf2 + ((0 * 48 + ntb + 2) * 64 + lane) * 8);

    f32x4 acc[4][3] = {};

    {   // stage chunk 0 (k 0..63)
        float4 v0 = *(const float4*)(Arowp);
        float4 v1 = *(const float4*)(Arowp + 4);
        int4 s;
        s.x = cvt_pk_bf16(v0.x, v0.y); s.y = cvt_pk_bf16(v0.z, v0.w);
        s.z = cvt_pk_bf16(v1.x, v1.y); s.w = cvt_pk_bf16(v1.z, v1.w);
        *(int4*)(&smem[srow * ASTR + sj * 8]) = s;
    }
    float4 lda0 = *(const float4*)(Arowp + 64);
    float4 lda1 = *(const float4*)(Arowp + 68);

    #pragma unroll
    for (int c = 0; c < 4; ++c) {          // K=256, KC=64
        barrier_lgkm();

        float4 ldn0, ldn1;
        if (c + 2 < 4) {
            const float* p = Arowp + (c + 2) * 64;
            ldn0 = *(const float4*)(p);
            ldn1 = *(const float4*)(p + 4);
        }

        bf16x8 bg0 = *(const bf16x8*)(wctf2 + (((2 * c + 1) * 48 + ntb + 0) * 64 + lane) * 8);
        bf16x8 bg1 = *(const bf16x8*)(wctf2 + (((2 * c + 1) * 48 + ntb + 1) * 64 + lane) * 8);
        bf16x8 bg2 = *(const bf16x8*)(wctf2 + (((2 * c + 1) * 48 + ntb + 2) * 64 + lane) * 8);

        const short* Ab = &smem[(c & 1) * ABUF];

        bf16x8 af[4];
        #pragma unroll
        for (int mt = 0; mt < 4; ++mt)
            af[mt] = *(const bf16x8*)(&Ab[(mt * 16 + l15) * ASTR + quad * 8]);
        #pragma unroll
        for (int mt = 0; mt < 4; ++mt) {
            acc[mt][0] = __builtin_amdgcn_mfma_f32_16x16x32_bf16(af[mt], bfc0, acc[mt][0], 0, 0, 0);
            acc[mt][1] = __builtin_amdgcn_mfma_f32_16x16x32_bf16(af[mt], bfc1, acc[mt][1], 0, 0, 0);
            acc[mt][2] = __builtin_amdgcn_mfma_f32_16x16x32_bf16(af[mt], bfc2, acc[mt][2], 0, 0, 0);
        }

        if (c + 1 < 4) {
            bfc0 = *(const bf16x8*)(wctf2 + (((2 * c + 2) * 48 + ntb + 0) * 64 + lane) * 8);
            bfc1 = *(const bf16x8*)(wctf2 + (((2 * c + 2) * 48 + ntb + 1) * 64 + lane) * 8);
            bfc2 = *(const bf16x8*)(wctf2 + (((2 * c + 2) * 48 + ntb + 2) * 64 + lane) * 8);
        }

        bf16x8 ag[4];
        #pragma unroll
        for (int mt = 0; mt < 4; ++mt)
            ag[mt] = *(const bf16x8*)(&Ab[(mt * 16 + l15) * ASTR + 32 + quad * 8]);
        #pragma unroll
        for (int mt = 0; mt < 4; ++mt) {
            acc[mt][0] = __builtin_amdgcn_mfma_f32_16x16x32_bf16(ag[mt], bg0, acc[mt][0], 0, 0, 0);
            acc[mt][1] = __builtin_amdgcn_mfma_f32_16x16x32_bf16(ag[mt], bg1, acc[mt][1], 0, 0, 0);
            acc[mt][2] = __builtin_amdgcn_mfma_f32_16x16x32_bf16(ag[mt], bg2, acc[mt][2], 0, 0, 0);
        }

        if (c + 1 < 4) {
            int4 s;
            s.x = cvt_pk_bf16(lda0.x, lda0.y); s.y = cvt_pk_bf16(lda0.z, lda0.w);
            s.z = cvt_pk_bf16(lda1.x, lda1.y); s.w = cvt_pk_bf16(lda1.z, lda1.w);
            *(int4*)(&smem[((c + 1) & 1) * ABUF + srow * ASTR + sj * 8]) = s;
        }
        if (c + 2 < 4) { lda0 = ldn0; lda1 = ldn1; }
    }

    // Epilogue: raw store (bias+relu applied in edge pass)
    char* rowbase = pre + (size_t)rowgrp * 64 * PRE_ROW;
    #pragma unroll
    for (int jn = 0; jn < 3; ++jn) {
        int col = (ntb + jn) * 16 + l15;       // global col 0..767
        if (col < 512) {
            #pragma unroll
            for (int mt = 0; mt < 4; ++mt)
                #pragma unroll
                for (int r = 0; r < 4; ++r) {
                    int row = mt * 16 + quad * 4 + r;
                    *(short*)(rowbase + (size_t)row * PRE_ROW + 2 * col) = f2bf(acc[mt][jn][r]);
                }
        } else {
            #pragma unroll
            for (int mt = 0; mt < 4; ++mt)
                #pragma unroll
                for (int r = 0; r < 4; ++r) {
                    int row = mt * 16 + quad * 4 + r;
                    *(float*)(rowbase + (size_t)row * PRE_ROW + 1024 + 4 * (col - 512)) = acc[mt][jn][r];
                }
        }
    }
}

// Edge pass: gather pre rows, add+bias+relu, edge-logit dot, GEMM2.
__global__ __launch_bounds__(256, 8)
void AttackHead_edge(const char* __restrict__ pre,
                     const float* __restrict__ army,
                     const int* __restrict__ edges,
                     const float* __restrict__ b1,
                     const float* __restrict__ W2,
                     const float* __restrict__ b2,
                     const float* __restrict__ a1,
                     const short* __restrict__ a2f,
                     const float* __restrict__ a2,
                     float* __restrict__ out) {
    __shared__ __align__(16) short Gs[TE * GSTR];   // 17408 B
    __shared__ int   srcn[TE], tgtn[TE];
    __shared__ float elog[TE], maxs[TE];
    __shared__ float b1s[256], W2s[256], a1s[128];

    const int tid = threadIdx.x;
    const int bb  = ((blockIdx.x & 7) << 10) | (blockIdx.x >> 3);
    const int bglob = bb >> 7;
    const long be0 = (long)bb * TE;

    if (tid < TE) {
        long be = be0 + tid;
        int src = edges[2 * be], tgt = edges[2 * be + 1];
        int sc = min(max(src, 0), NN - 1);
        int tc = min(max(tgt, 0), NN - 1);
        srcn[tid] = sc; tgtn[tid] = tc;
        float sa = army[(size_t)bglob * NN + sc];
        float ta = army[(size_t)bglob * NN + tc];
        bool valid = (src >= 0) && (tgt >= 0);
        bool bad   = valid && (sa <= 2.0f || ta >= 3.0f * sa);
        bool selfe = valid && (src == tgt);
        elog[tid] = b2[0] - (bad ? 1.0f : 0.0f) - (selfe ? 100.0f : 0.0f);
        maxs[tid] = sa - 1.0f;
    }
    b1s[tid] = b1[tid];
    W2s[tid] = W2[tid];
    if (tid < 128) a1s[tid] = a1[tid];
    __syncthreads();

    const int e = tid & 63;      // edge within block
    const int j = tid >> 6;      // quarter 0..3 (== wave id)
    const char* sp = pre + (size_t)((size_t)bglob * NN + srcn[e]) * PRE_ROW;
    const char* tp = pre + (size_t)((size_t)bglob * NN + tgtn[e]) * PRE_ROW;

    // h-part: cols [j*64, j*64+64): Hsrc from sp bytes [0,512), Htgt from tp [512,1024)
    float dot = 0.0f;
    #pragma unroll
    for (int b = 0; b < 8; ++b) {
        bf16x8 hs = *(const bf16x8*)(sp + j * 128 + b * 16);
        bf16x8 ht = *(const bf16x8*)(tp + 512 + j * 128 + b * 16);
        #pragma unroll
        for (int i = 0; i < 8; ++i) {
            int col = j * 64 + b * 8 + i;
            float h = fmaxf(bf2f(hs[i]) + bf2f(ht[i]) + b1s[col], 0.0f);
            dot = fmaf(h, W2s[col], dot);
        }
    }
    // g-part: cols [j*32, j*32+32): Gsrc f32 sp[1024+j*128 ..), Gtgt tp[1536+j*128 ..)
    #pragma unroll
    for (int b = 0; b < 8; ++b) {
        float4 gs = *(const float4*)(sp + 1024 + j * 128 + b * 16);
        float4 gt = *(const float4*)(tp + 1536 + j * 128 + b * 16);
        int gc = j * 32 + b * 4;
        float g0 = fmaxf(gs.x + gt.x + a1s[gc + 0], 0.0f);
        float g1 = fmaxf(gs.y + gt.y + a1s[gc + 1], 0.0f);
        float g2 = fmaxf(gs.z + gt.z + a1s[gc + 2], 0.0f);
        float g3 = fmaxf(gs.w + gt.w + a1s[gc + 3], 0.0f);
        int2 pk;
        pk.x = cvt_pk_bf16(g0, g1);
        pk.y = cvt_pk_bf16(g2, g3);
        *(int2*)(&Gs[e * GSTR + gc]) = pk;
    }
    atomicAdd(&elog[e], dot);
    __syncthreads();

    // GEMM2: relu(g)[64,128] @ A2[128,64]; wave j = m-tile
    const int lane = tid & 63;
    const int quad = lane >> 4;
    const int l15  = lane & 15;
    f32x4 acc2[4] = {};
    #pragma unroll
    for (int ks = 0; ks < 4; ++ks) {
        bf16x8 ga = *(const bf16x8*)(&Gs[(j * 16 + l15) * GSTR + ks * 32 + quad * 8]);
        #pragma unroll
        for (int nt2 = 0; nt2 < 4; ++nt2) {
            bf16x8 bv = *(const bf16x8*)(a2f + ((ks * 4 + nt2) * 64 + lane) * 8);
            acc2[nt2] = __builtin_amdgcn_mfma_f32_16x16x32_bf16(ga, bv, acc2[nt2], 0, 0, 0);
        }
    }

    if (tid < TE) out[be0 + tid] = elog[tid];

    #pragma unroll
    for (int nt2 = 0; nt2 < 4; ++nt2) {
        int col = nt2 * 16 + l15;
        float a2v = a2[col];
        #pragma unroll
        for (int r = 0; r < 4; ++r) {
            int grow = j * 16 + quad * 4 + r;
            float val = acc2[nt2][r] + a2v;
            if ((float)col > maxs[grow]) val = -1e9f;
            out[(size_t)BE_TOT + (size_t)(be0 + grow) * MM + col] = val;
        }
    }
}

extern "C" void kernel_launch(void* const* d_in, const int* in_sizes, int n_in,
                              void* d_out, int out_size, void* d_ws, size_t ws_size,
                              hipStream_t stream) {
    const float* nodes = (const float*)d_in[0];
    const float* army  = (const float*)d_in[1];
    const int*   edges = (const int*)d_in[2];
    const float* W1    = (const float*)d_in[3];
    const float* b1    = (const float*)d_in[4];
    const float* W2    = (const float*)d_in[5];
    const float* b2    = (const float*)d_in[6];
    const float* A1    = (const float*)d_in[7];
    const float* a1    = (const float*)d_in[8];
    const float* A2    = (const float*)d_in[9];
    const float* a2    = (const float*)d_in[10];
    float* out = (float*)d_out;

    int nblocks = BE_TOT / TE;   // 8192

    if (ws_size >= WS_BIG) {
        // New path: per-node precompute + light edge pass
        short* wctf2 = (short*)d_ws;
        short* a2fp  = wctf2 + WCTF_ELEMS;
        char*  pre   = (char*)d_ws + WS_FRAG;   // 409600 % 2048 == 0 -> rows aligned
        AttackHead_prep2<<<800, 256, 0, stream>>>(W1, A1, A2, wctf2, a2fp);
        AttackHead_pregemm<<<8192, 512, 0, stream>>>(nodes, wctf2, pre);
        AttackHead_edge<<<8192, 256, 0, stream>>>(pre, army, edges, b1, W2, b2,
                                                  a1, a2fp, a2, out);
    } else if (ws_size >= WS_FRAG) {
        short* wctf = (short*)d_ws;
        short* a2fp = wctf + WCTF_ELEMS;
        AttackHead_prep<<<800, 256, 0, stream>>>(W1, A1, A2, wctf, a2fp);
        AttackHead_main<true><<<nblocks, BLOCK, 0, stream>>>(
            nodes, army, edges, W1, b1, W2, b2, A1, a1, A2, a2, wctf, a2fp, out);
    } else {
        AttackHead_main<false><<<nblocks, BLOCK, 0, stream>>>(
            nodes, army, edges, W1, b1, W2, b2, A1, a1, A2, a2,
            (const short*)nullptr, (const short*)nullptr, out);
    }
}

// Round 5
// 710.803 us; speedup vs baseline: 1.2962x; 1.2962x over previous
//
#include <hip/hip_runtime.h>

// Problem constants
#define BB   64
#define NN   4096
#define EE   8192
#define DD   256
#define HH   256
#define MM   64
#define K1   512          // 2*D
#define NC   384          // H + 128 fused GEMM1 cols
#define TE   32           // edges per block (halved: 2x3 acc -> <=64 regs -> 8 waves/SIMD)
#define BLOCK 512         // 8 waves
#define KC   64           // k-elems per chunk (2 MFMA k-steps)
#define NCHUNK 8          // K1/KC
#define ASTR 88           // shorts per A row (64 + 24 pad): 176B stride
#define GSTR 136          // shorts per Gs row (128 + 8 pad)
#define ABUF (TE * ASTR)  // 2816 shorts per A buffer
#define SMEM_SHORTS (2 * ABUF)  // 5632 shorts; Gs needs 32*136=4352 < 5632
#define BE_TOT (BB * EE)  // 524288
#define NBLK (BE_TOT / TE)  // 16384
#define WCTF_ELEMS (NC * K1)   // 196608
#define A2F_ELEMS  (128 * MM)  // 8192
#define WS_NEEDED ((size_t)(WCTF_ELEMS + A2F_ELEMS) * sizeof(short))  // 409600

typedef float f32x4 __attribute__((ext_vector_type(4)));
typedef short bf16x8 __attribute__((ext_vector_type(8)));

__device__ __forceinline__ short f2bf(float f) {
    unsigned u = __float_as_uint(f);
    unsigned r = (u + 0x7fffu + ((u >> 16) & 1u)) >> 16;
    return (short)r;
}
// Packed f32->bf16 RNE conversion: 2 floats -> 1 dword in ONE VALU op.
__device__ __forceinline__ int cvt_pk_bf16(float lo, float hi) {
    int r;
    asm("v_cvt_pk_bf16_f32 %0, %1, %2" : "=v"(r) : "v"(lo), "v"(hi));
    return r;
}
// Barrier that only drains LDS ops — global loads (gather/B-frag prefetch,
// landing in VGPRs) stay in flight across the barrier.
__device__ __forceinline__ void barrier_lgkm() {
    asm volatile("s_waitcnt lgkmcnt(0)\n\ts_barrier" ::: "memory");
}

// Prep: write weights in MFMA B-fragment order (bf16).
__global__ void AttackHead_prep(const float* __restrict__ W1,
                                const float* __restrict__ A1,
                                const float* __restrict__ A2,
                                short* __restrict__ wctf,
                                short* __restrict__ a2f) {
    int t = blockIdx.x * 256 + threadIdx.x;
    if (t < 131072) {                       // W1 [512][256], coalesced read
        int k = t >> 8, n = t & 255;
        int c = k >> 5, kr = k & 31, quad = kr >> 3, j = kr & 7;
        int nt = n >> 4, l15 = n & 15;
        wctf[((c * 24 + nt) * 64 + quad * 16 + l15) * 8 + j] = f2bf(W1[t]);
    } else if (t < 131072 + 65536) {        // A1 [512][128]
        int t2 = t - 131072;
        int k = t2 >> 7, n = 256 + (t2 & 127);
        int c = k >> 5, kr = k & 31, quad = kr >> 3, j = kr & 7;
        int nt = n >> 4, l15 = n & 15;
        wctf[((c * 24 + nt) * 64 + quad * 16 + l15) * 8 + j] = f2bf(A1[t2]);
    } else if (t < 131072 + 65536 + 8192) { // A2 [128][64]
        int t3 = t - 131072 - 65536;
        int k = t3 >> 6, n = t3 & 63;
        int ks = k >> 5, kr = k & 31, quad = kr >> 3, j = kr & 7;
        int nt2 = n >> 4, l15 = n & 15;
        a2f[((ks * 4 + nt2) * 64 + quad * 16 + l15) * 8 + j] = f2bf(A2[t3]);
    }
}

template <bool USE_WS>
__device__ __forceinline__ bf16x8 load_bfrag(const short* __restrict__ wf,
                                             const float* __restrict__ W1,
                                             const float* __restrict__ A1,
                                             int c, int nt, int lane) {
    if (USE_WS) {
        return *(const bf16x8*)(wf + ((c * 24 + nt) * 64 + lane) * 8);
    } else {
        int l15 = lane & 15, quad = lane >> 4;
        int n = nt * 16 + l15;
        bf16x8 r;
        #pragma unroll
        for (int j = 0; j < 8; ++j) {
            int k = c * 32 + quad * 8 + j;
            float v = (n < HH) ? W1[k * HH + n] : A1[k * 128 + (n - HH)];
            r[j] = f2bf(v);
        }
        return r;
    }
}

template <bool USE_WS>
__device__ __forceinline__ bf16x8 load_a2frag(const short* __restrict__ a2f,
                                              const float* __restrict__ A2,
                                              int ks, int nt2, int lane) {
    if (USE_WS) {
        return *(const bf16x8*)(a2f + ((ks * 4 + nt2) * 64 + lane) * 8);
    } else {
        int l15 = lane & 15, quad = lane >> 4;
        int n = nt2 * 16 + l15;
        bf16x8 r;
        #pragma unroll
        for (int j = 0; j < 8; ++j) {
            int k = ks * 32 + quad * 8 + j;
            r[j] = f2bf(A2[k * MM + n]);
        }
        return r;
    }
}

template <bool USE_WS>
__global__ __launch_bounds__(BLOCK, 8)   // force <=64 regs -> 8 waves/SIMD
void AttackHead_main(const float* __restrict__ nodes,
                     const float* __restrict__ army,
                     const int* __restrict__ edges,
                     const float* __restrict__ W1,
                     const float* __restrict__ b1,
                     const float* __restrict__ W2,
                     const float* __restrict__ b2,
                     const float* __restrict__ A1,
                     const float* __restrict__ a1,
                     const float* __restrict__ A2,
                     const float* __restrict__ a2,
                     const short* __restrict__ wctf,
                     const short* __restrict__ a2f,
                     float* __restrict__ out) {
    // LDS: union of {2 A-buffers (2*2816 shorts)} and {Gs 32x136=4352 shorts}
    __shared__ __align__(16) short smem[SMEM_SHORTS];   // 11264 B
    __shared__ int   srcn[TE], tgtn[TE];
    __shared__ float elog[TE], maxs[TE];

    const int tid = threadIdx.x;
    // XCD-contiguous swizzle: each XCD walks 8 consecutive batches -> the
    // batch's 4MB node set stays L2-resident (R1: FETCH 465->205 MB).
    const int bb  = ((blockIdx.x & 7) << 11) | (blockIdx.x >> 3);
    const int bglob = bb >> 8;              // 256 blocks per batch
    const long be0 = (long)bb * TE;

    // ---- Phase 0: edge scalars ----
    if (tid < TE) {
        long be = be0 + tid;
        int src = edges[2 * be], tgt = edges[2 * be + 1];
        int sc = min(max(src, 0), NN - 1);
        int tc = min(max(tgt, 0), NN - 1);
        srcn[tid] = sc; tgtn[tid] = tc;
        float sa = army[(size_t)bglob * NN + sc];
        float ta = army[(size_t)bglob * NN + tc];
        bool valid = (src >= 0) && (tgt >= 0);
        bool bad   = valid && (sa <= 2.0f || ta >= 3.0f * sa);
        bool selfe = valid && (src == tgt);
        elog[tid] = b2[0] - (bad ? 1.0f : 0.0f) - (selfe ? 100.0f : 0.0f);
        maxs[tid] = sa - 1.0f;
    }
    __syncthreads();

    const int w    = tid >> 6;     // wave 0..7
    const int lane = tid & 63;
    const int quad = lane >> 4;
    const int l15  = lane & 15;

    // staging role: 16 threads per row, 4 floats each (KC=64 per chunk)
    const int srow = tid >> 4;     // 0..31
    const int sj   = tid & 15;     // float4 index within 64-float chunk
    const size_t nbase_g = (size_t)bglob * NN;
    // hoisted gather bases: per-chunk addresses become compile-time offsets
    const float* srcp = nodes + (nbase_g + (size_t)srcn[srow]) * DD + sj * 4;
    const float* tgtp = nodes + (nbase_g + (size_t)tgtn[srow]) * DD + sj * 4;

    f32x4 acc[2][3] = {};          // [m-tile][n-tile]; wave's n-tiles = w*3 + jn

    // ---- Prologue: stage chunk 0, issue chunk 1 ----
    {
        float4 v = *(const float4*)(srcp);
        int2 s;
        s.x = cvt_pk_bf16(v.x, v.y); s.y = cvt_pk_bf16(v.z, v.w);
        *(int2*)(&smem[srow * ASTR + sj * 4]) = s;
    }
    float4 lda = *(const float4*)(srcp + 64);

    #pragma unroll
    for (int c = 0; c < NCHUNK; ++c) {
        barrier_lgkm();            // buf[c&1] ready; global prefetches stay in flight

        // distance-2 gather prefetch (chunks 0-3 src, 4-7 tgt)
        float4 ldn;
        if (c + 2 < NCHUNK)
            ldn = *(const float4*)((((c + 2) < 4) ? srcp : tgtp) + ((c + 2) & 3) * 64);

        const short* Ab = &smem[(c & 1) * ABUF];
        #pragma unroll
        for (int kk = 0; kk < 2; ++kk) {
            bf16x8 b0 = load_bfrag<USE_WS>(wctf, W1, A1, 2 * c + kk, w * 3 + 0, lane);
            bf16x8 b1f = load_bfrag<USE_WS>(wctf, W1, A1, 2 * c + kk, w * 3 + 1, lane);
            bf16x8 b2f = load_bfrag<USE_WS>(wctf, W1, A1, 2 * c + kk, w * 3 + 2, lane);
            bf16x8 a0 = *(const bf16x8*)(&Ab[(0 * 16 + l15) * ASTR + kk * 32 + quad * 8]);
            bf16x8 a1f = *(const bf16x8*)(&Ab[(1 * 16 + l15) * ASTR + kk * 32 + quad * 8]);
            acc[0][0] = __builtin_amdgcn_mfma_f32_16x16x32_bf16(a0, b0, acc[0][0], 0, 0, 0);
            acc[0][1] = __builtin_amdgcn_mfma_f32_16x16x32_bf16(a0, b1f, acc[0][1], 0, 0, 0);
            acc[0][2] = __builtin_amdgcn_mfma_f32_16x16x32_bf16(a0, b2f, acc[0][2], 0, 0, 0);
            acc[1][0] = __builtin_amdgcn_mfma_f32_16x16x32_bf16(a1f, b0, acc[1][0], 0, 0, 0);
            acc[1][1] = __builtin_amdgcn_mfma_f32_16x16x32_bf16(a1f, b1f, acc[1][1], 0, 0, 0);
            acc[1][2] = __builtin_amdgcn_mfma_f32_16x16x32_bf16(a1f, b2f, acc[1][2], 0, 0, 0);
        }

        // stage chunk c+1 into the other buffer (safe: lgkm barrier at iter
        // start drained last iter's reads of it)
        if (c + 1 < NCHUNK) {
            int2 s;
            s.x = cvt_pk_bf16(lda.x, lda.y); s.y = cvt_pk_bf16(lda.z, lda.w);
            *(int2*)(&smem[((c + 1) & 1) * ABUF + srow * ASTR + sj * 4]) = s;
        }
        if (c + 2 < NCHUNK) lda = ldn;
    }

    __syncthreads();   // full drain: all A-buffer reads done; Gs reuse safe

    // ---- Epilogue 1: bias+relu; edge-logit partials; relu(g) -> Gs ----
    short* Gs = smem;
    float ep[2][4] = {};
    #pragma unroll
    for (int jn = 0; jn < 3; ++jn) {
        int ct = (w * 3 + jn) * 16 + l15;
        float bias = (ct < HH) ? b1[ct] : a1[ct - HH];
        if (ct < HH) {
            float w2v = W2[ct];
            #pragma unroll
            for (int mt = 0; mt < 2; ++mt)
                #pragma unroll
                for (int r = 0; r < 4; ++r) {
                    float h = fmaxf(acc[mt][jn][r] + bias, 0.0f);
                    ep[mt][r] += h * w2v;
                }
        } else {
            int gc = ct - HH;
            #pragma unroll
            for (int mt = 0; mt < 2; ++mt)
                #pragma unroll
                for (int r = 0; r < 4; ++r) {
                    float g = fmaxf(acc[mt][jn][r] + bias, 0.0f);
                    Gs[(mt * 16 + quad * 4 + r) * GSTR + gc] = f2bf(g);
                }
        }
    }
    if (w < 6) {   // waves 6,7 have no h-columns
        #pragma unroll
        for (int msk = 1; msk <= 8; msk <<= 1)
            #pragma unroll
            for (int mt = 0; mt < 2; ++mt)
                #pragma unroll
                for (int r = 0; r < 4; ++r)
                    ep[mt][r] += __shfl_xor(ep[mt][r], msk, 64);
        if (l15 == 0) {
            #pragma unroll
            for (int mt = 0; mt < 2; ++mt)
                #pragma unroll
                for (int r = 0; r < 4; ++r)
                    atomicAdd(&elog[mt * 16 + quad * 4 + r], ep[mt][r]);
        }
    }
    __syncthreads();

    // ---- GEMM2: relu(g)[32,128] @ A2[128,64]; wave = (m-tile, n-tile) ----
    const int mt2 = w >> 2;      // m-tile 0..1
    const int nt2 = w & 3;       // n-tile 0..3
    f32x4 acc2 = {};
    #pragma unroll
    for (int ks = 0; ks < 4; ++ks) {
        bf16x8 ga = *(const bf16x8*)(&Gs[(mt2 * 16 + l15) * GSTR + ks * 32 + quad * 8]);
        bf16x8 bv = load_a2frag<USE_WS>(a2f, A2, ks, nt2, lane);
        acc2 = __builtin_amdgcn_mfma_f32_16x16x32_bf16(ga, bv, acc2, 0, 0, 0);
    }

    // ---- Outputs ----
    if (tid < TE) out[be0 + tid] = elog[tid];

    {
        int col = nt2 * 16 + l15;
        float a2v = a2[col];
        #pragma unroll
        for (int r = 0; r < 4; ++r) {
            int grow = mt2 * 16 + quad * 4 + r;
            float val = acc2[r] + a2v;
            if ((float)col > maxs[grow]) val = -1e9f;
            out[(size_t)BE_TOT + (size_t)(be0 + grow) * MM + col] = val;
        }
    }
}

extern "C" void kernel_launch(void* const* d_in, const int* in_sizes, int n_in,
                              void* d_out, int out_size, void* d_ws, size_t ws_size,
                              hipStream_t stream) {
    const float* nodes = (const float*)d_in[0];
    const float* army  = (const float*)d_in[1];
    const int*   edges = (const int*)d_in[2];
    const float* W1    = (const float*)d_in[3];
    const float* b1    = (const float*)d_in[4];
    const float* W2    = (const float*)d_in[5];
    const float* b2    = (const float*)d_in[6];
    const float* A1    = (const float*)d_in[7];
    const float* a1    = (const float*)d_in[8];
    const float* A2    = (const float*)d_in[9];
    const float* a2    = (const float*)d_in[10];
    float* out = (float*)d_out;

    if (ws_size >= WS_NEEDED) {
        short* wctf = (short*)d_ws;
        short* a2f  = wctf + WCTF_ELEMS;
        AttackHead_prep<<<800, 256, 0, stream>>>(W1, A1, A2, wctf, a2f);
        AttackHead_main<true><<<NBLK, BLOCK, 0, stream>>>(
            nodes, army, edges, W1, b1, W2, b2, A1, a1, A2, a2, wctf, a2f, out);
    } else {
        AttackHead_main<false><<<NBLK, BLOCK, 0, stream>>>(
            nodes, army, edges, W1, b1, W2, b2, A1, a1, A2, a2,
            (const short*)nullptr, (const short*)nullptr, out);
    }
}